// Round 7
// baseline (362.689 us; speedup 1.0000x reference)
//
#include <hip/hip_runtime.h>
#include <hip/hip_bf16.h>

typedef unsigned short u16;
typedef unsigned int u32;
typedef __attribute__((ext_vector_type(8))) short bf16x8;
typedef __attribute__((ext_vector_type(4))) float f32x4;

#define S_LEN 4096
#define DHEAD 128
#define NHEAD 8
#define NBATCH 2
#define NCHUNKF 576   // per (b,h): sum_{qt} ceil((qt+1)/16)

__device__ __forceinline__ u16 f2b(float f) {
  __hip_bfloat16 h = __float2bfloat16(f);
  return *(u16*)&h;
}

__device__ __forceinline__ f32x4 mfma16(bf16x8 a, bf16x8 b, f32x4 c) {
  return __builtin_amdgcn_mfma_f32_16x16x32_bf16(a, b, c, 0, 0, 0);
}

__device__ __forceinline__ f32x4 zero4() { f32x4 z = {0.f, 0.f, 0.f, 0.f}; return z; }

// ---------------- converts ----------------
__global__ void k_conv_x(const float* __restrict__ x, u16* __restrict__ xb,
                         u16* __restrict__ xT) {
  int idx = blockIdx.x * blockDim.x + threadIdx.x;
  float v = x[idx];
  u16 bv = f2b(v);
  xb[idx] = bv;
  int d = idx & 127;
  int bs = idx >> 7;
  int b = bs >> 12;
  int s = bs & 4095;
  xT[((size_t)b * DHEAD + d) * S_LEN + s] = bv;
}

__global__ void k_conv_w(const float* __restrict__ Wq, const float* __restrict__ Wk,
                         const float* __restrict__ Wo, u16* __restrict__ Wqt,
                         u16* __restrict__ Wkt, u16* __restrict__ WoB) {
  int idx = blockIdx.x * blockDim.x + threadIdx.x;
  int h = idx >> 14;
  int d = (idx >> 7) & 127;
  int e = idx & 127;
  int t = (h << 14) + (e << 7) + d;
  Wqt[t] = f2b(Wq[idx]);
  Wkt[t] = f2b(Wk[idx]);
  WoB[idx] = f2b(Wo[idx]);
}

// ---------------- Q/K projection: 4 waves/block ----------------
__global__ __launch_bounds__(256) void k_proj(const u16* __restrict__ xb,
                                              const u16* __restrict__ Wqt,
                                              const u16* __restrict__ Wkt,
                                              u16* __restrict__ Qb, u16* __restrict__ Kb) {
  int wid = threadIdx.x >> 6;
  int lane = threadIdx.x & 63;
  int qt = blockIdx.x * 4 + wid;
  int h = blockIdx.y, z = blockIdx.z;
  int b = z >> 1, w = z & 1;
  int row16 = lane & 15, kgrp = lane >> 4;
  int sb = qt * 32;
  const u16* xp = xb + ((size_t)b * S_LEN + sb) * DHEAD;
  bf16x8 a[2][4];
#pragma unroll
  for (int r = 0; r < 2; ++r)
#pragma unroll
    for (int kc = 0; kc < 4; ++kc)
      a[r][kc] = *(const bf16x8*)(xp + (r * 16 + row16) * DHEAD + kc * 32 + kgrp * 8);

  const u16* Wt = (w == 0 ? Wqt : Wkt) + (size_t)h * DHEAD * DHEAD;
  u16* Out = (w == 0 ? Qb : Kb) + ((size_t)(b * NHEAD + h) * S_LEN + sb) * DHEAD;
  f32x4 acc[2][8];
#pragma unroll
  for (int r = 0; r < 2; ++r)
#pragma unroll
    for (int nc = 0; nc < 8; ++nc) acc[r][nc] = zero4();
#pragma unroll
  for (int kc = 0; kc < 4; ++kc)
#pragma unroll
    for (int nc = 0; nc < 8; ++nc) {
      bf16x8 bw = *(const bf16x8*)(Wt + (nc * 16 + row16) * DHEAD + kc * 32 + kgrp * 8);
      acc[0][nc] = mfma16(a[0][kc], bw, acc[0][nc]);
      acc[1][nc] = mfma16(a[1][kc], bw, acc[1][nc]);
    }
#pragma unroll
  for (int r = 0; r < 2; ++r)
#pragma unroll
    for (int nc = 0; nc < 8; ++nc)
#pragma unroll
      for (int i = 0; i < 4; ++i)
        Out[(size_t)(r * 16 + kgrp * 4 + i) * DHEAD + nc * 16 + row16] =
            f2b(acc[r][nc][i]);
}

// ---------------- causal flash attention, split-K, coalesced partials --------
// Each block (1 wave) = one (b,h,qt,chunk): <=16 key-tiles (512 keys).
// Clip-before-softmax => partials combine by plain addition.
// Partial y written in MFMA-fragment order [r][nc][lane] -> 1KB/instr coalesced.
__global__ __launch_bounds__(64) void k_attn(const u16* __restrict__ Qb,
                                             const u16* __restrict__ Kb,
                                             const u16* __restrict__ xT,
                                             float* __restrict__ yPart,
                                             float* __restrict__ rsPart) {
  int bid = blockIdx.x;                      // 0..9215
  int xcd = bid & 7;
  int j = bid >> 3;                          // 0..1151
  int pair = xcd + (j >= NCHUNKF ? 8 : 0);   // 0..15 ; same (b,h) stays on one XCD
  int cf = (j >= NCHUNKF) ? j - NCHUNKF : j; // 0..575
  int b = pair >> 3, h = pair & 7;

  // invert cf -> (qt, c):  F(qt) = 8g(g+1) + (qt-16g)(g+1),  g = qt>>4
  int g = 0;
#pragma unroll
  for (int t = 1; t < 8; ++t)
    if (cf >= 8 * t * (t + 1)) g = t;
  int rem = cf - 8 * g * (g + 1);
  int qdiv = rem / (g + 1);
  int qt = 16 * g + qdiv;
  int c = rem - qdiv * (g + 1);

  int kt0 = c * 16;
  int klast = (c == g) ? qt : kt0 + 15;

  int lane = threadIdx.x;
  int row16 = lane & 15, kgrp = lane >> 4;
  int qb0 = qt * 32;

  const u16* Qp = Qb + ((size_t)(b * NHEAD + h) * S_LEN + qb0) * DHEAD;
  const u16* Kp = Kb + (size_t)(b * NHEAD + h) * S_LEN * DHEAD;
  const u16* Vt = xT + (size_t)b * DHEAD * S_LEN;

  bf16x8 aq[2][4];
#pragma unroll
  for (int r = 0; r < 2; ++r)
#pragma unroll
    for (int kc = 0; kc < 4; ++kc)
      aq[r][kc] = *(const bf16x8*)(Qp + (r * 16 + row16) * DHEAD + kc * 32 + kgrp * 8);

  f32x4 y[2][8];
#pragma unroll
  for (int r = 0; r < 2; ++r)
#pragma unroll
    for (int nc = 0; nc < 8; ++nc) y[r][nc] = zero4();
  f32x4 rs[2];
  rs[0] = zero4();
  rs[1] = zero4();

  __shared__ __align__(16) u16 plds[2][32][40];

  bf16x8 kbufA[8], kbufB[8];

  auto loadK = [&](bf16x8 (&dst)[8], int k0) {
#pragma unroll
    for (int nk = 0; nk < 2; ++nk)
#pragma unroll
      for (int kc = 0; kc < 4; ++kc)
        dst[nk * 4 + kc] = *(const bf16x8*)(Kp + (size_t)(k0 + nk * 16 + row16) * DHEAD +
                                            kc * 32 + kgrp * 8);
  };

  const float c2 = 0.12754274816295166f;    // (1/sqrt(128)) * log2(e)
  const float clip2 = 14.426950408889634f;  // 10 * log2(e)

  auto body = [&](bf16x8 (&kc_)[8], bf16x8 (&kn_)[8], int kt) {
    int k0 = kt * 32;
    int cur = kt & 1;
    bf16x8 vreg[8];
#pragma unroll
    for (int nc = 0; nc < 8; ++nc)
      vreg[nc] = *(const bf16x8*)(Vt + (size_t)(nc * 16 + row16) * S_LEN + k0 + kgrp * 8);
    int kn0 = (kt < klast) ? k0 + 32 : k0;
    loadK(kn_, kn0);

    f32x4 sc[2][2];
    sc[0][0] = zero4(); sc[0][1] = zero4(); sc[1][0] = zero4(); sc[1][1] = zero4();
#pragma unroll
    for (int nk = 0; nk < 2; ++nk)
#pragma unroll
      for (int kcc = 0; kcc < 4; ++kcc) {
        sc[0][nk] = mfma16(aq[0][kcc], kc_[nk * 4 + kcc], sc[0][nk]);
        sc[1][nk] = mfma16(aq[1][kcc], kc_[nk * 4 + kcc], sc[1][nk]);
      }

#pragma unroll
    for (int r = 0; r < 2; ++r)
#pragma unroll
      for (int nk = 0; nk < 2; ++nk) {
        int key = k0 + nk * 16 + row16;
#pragma unroll
        for (int i = 0; i < 4; ++i) {
          float v = sc[r][nk][i] * c2;
          v = fminf(fmaxf(v, -clip2), clip2);
          float pcur = __builtin_amdgcn_exp2f(v);
          int qrow = qb0 + r * 16 + kgrp * 4 + i;
          pcur = (key > qrow) ? 0.0f : pcur;   // branchless; only fires on diag tile
          rs[r][i] += pcur;
          plds[cur][r * 16 + kgrp * 4 + i][nk * 16 + row16] = f2b(pcur);
        }
      }
    bf16x8 ap0 = *(const bf16x8*)&plds[cur][row16][kgrp * 8];
    bf16x8 ap1 = *(const bf16x8*)&plds[cur][16 + row16][kgrp * 8];
#pragma unroll
    for (int nc = 0; nc < 8; ++nc) {
      y[0][nc] = mfma16(ap0, vreg[nc], y[0][nc]);
      y[1][nc] = mfma16(ap1, vreg[nc], y[1][nc]);
    }
  };

  loadK(kbufA, kt0 * 32);
  int kt = kt0;
  while (true) {
    body(kbufA, kbufB, kt);
    if (kt == klast) break;
    ++kt;
    body(kbufB, kbufA, kt);
    if (kt == klast) break;
    ++kt;
  }

  // reduce rs over the 16 row16 lanes of each kgrp group
#pragma unroll
  for (int r = 0; r < 2; ++r)
#pragma unroll
    for (int i = 0; i < 4; ++i) {
      float v = rs[r][i];
      v += __shfl_xor(v, 1, 64);
      v += __shfl_xor(v, 2, 64);
      v += __shfl_xor(v, 4, 64);
      v += __shfl_xor(v, 8, 64);
      rs[r][i] = v;
    }

  size_t slot = (size_t)pair * NCHUNKF + cf;
  float* yP = yPart + slot * (32 * 128);
  float* rsP = rsPart + slot * 32;
  if (row16 == 0) {
#pragma unroll
    for (int r = 0; r < 2; ++r)
#pragma unroll
      for (int i = 0; i < 4; ++i) rsP[r * 16 + kgrp * 4 + i] = rs[r][i];
  }
  // fragment-order coalesced write: each store = 64 lanes x 16B = 1KB contiguous
#pragma unroll
  for (int r = 0; r < 2; ++r)
#pragma unroll
    for (int nc = 0; nc < 8; ++nc)
      *(f32x4*)(yP + ((r * 8 + nc) * 64 + lane) * 4) = y[r][nc];
}

// ---------------- combine: 4 waves/block, fragment-order reads ----------------
__global__ __launch_bounds__(256) void k_comb(const float* __restrict__ yPart,
                                              const float* __restrict__ rsPart,
                                              u16* __restrict__ Yb) {
  int wid = threadIdx.x >> 6;
  int lane = threadIdx.x & 63;
  int row16 = lane & 15, kgrp = lane >> 4;
  int v0 = blockIdx.x * 4 + wid;  // 0..2047
  int pair = v0 >> 7, qt = v0 & 127;
  int b = pair >> 3, h = pair & 7;
  int g = qt >> 4;
  int nch = g + 1;
  int cf0 = 8 * g * (g + 1) + (qt - 16 * g) * (g + 1);
  size_t slot0 = (size_t)pair * NCHUNKF + cf0;
  const float* base = yPart + slot0 * (32 * 128);
  const float* rbase = rsPart + slot0 * 32;

  __shared__ float rinv[4][32];
  if (lane < 32) {
    float s = 0.f;
    for (int cc = 0; cc < nch; ++cc) s += rbase[cc * 32 + lane];
    rinv[wid][lane] = 1.0f / s;
  }

  f32x4 acc[2][8];
#pragma unroll
  for (int r = 0; r < 2; ++r)
#pragma unroll
    for (int nc = 0; nc < 8; ++nc)
      acc[r][nc] = *(const f32x4*)(base + ((r * 8 + nc) * 64 + lane) * 4);
  for (int cc = 1; cc < nch; ++cc) {
    const float* p = base + (size_t)cc * 4096;
#pragma unroll
    for (int r = 0; r < 2; ++r)
#pragma unroll
      for (int nc = 0; nc < 8; ++nc)
        acc[r][nc] += *(const f32x4*)(p + ((r * 8 + nc) * 64 + lane) * 4);
  }

  u16* Yp = Yb + ((size_t)b * S_LEN + qt * 32) * (NHEAD * DHEAD) + h * DHEAD;
#pragma unroll
  for (int r = 0; r < 2; ++r)
#pragma unroll
    for (int nc = 0; nc < 8; ++nc)
#pragma unroll
      for (int i = 0; i < 4; ++i)
        Yp[(size_t)(r * 16 + kgrp * 4 + i) * (NHEAD * DHEAD) + nc * 16 + row16] =
            f2b(acc[r][nc][i] * rinv[wid][r * 16 + kgrp * 4 + i]);
}

// ---------------- output projection: 4 waves/block ----------------
__global__ __launch_bounds__(256) void k_oproj(const u16* __restrict__ Yb,
                                               const u16* __restrict__ WoB,
                                               float* __restrict__ out) {
  int wid = threadIdx.x >> 6;
  int lane = threadIdx.x & 63;
  int mb = (blockIdx.x * 4 + wid) * 32 + blockIdx.y * 16;
  int nb = blockIdx.z * 64;
  int row16 = lane & 15, kgrp = lane >> 4;
  f32x4 acc[4];
#pragma unroll
  for (int nc = 0; nc < 4; ++nc) acc[nc] = zero4();
#pragma unroll 4
  for (int kc = 0; kc < 32; ++kc) {
    bf16x8 a0 = *(const bf16x8*)(Yb + (size_t)(mb + row16) * 1024 + kc * 32 + kgrp * 8);
#pragma unroll
    for (int nc = 0; nc < 4; ++nc) {
      bf16x8 bw =
          *(const bf16x8*)(WoB + (size_t)(nb + nc * 16 + row16) * 1024 + kc * 32 + kgrp * 8);
      acc[nc] = mfma16(a0, bw, acc[nc]);
    }
  }
#pragma unroll
  for (int nc = 0; nc < 4; ++nc)
#pragma unroll
    for (int i = 0; i < 4; ++i)
      out[(size_t)(mb + kgrp * 4 + i) * DHEAD + nb + nc * 16 + row16] = acc[nc][i];
}

extern "C" void kernel_launch(void* const* d_in, const int* in_sizes, int n_in,
                              void* d_out, int out_size, void* d_ws, size_t ws_size,
                              hipStream_t stream) {
  const float* x = (const float*)d_in[0];
  const float* Wq = (const float*)d_in[1];
  const float* Wk = (const float*)d_in[2];
  const float* Wo = (const float*)d_in[3];
  float* out = (float*)d_out;

  char* ws = (char*)d_ws;
  size_t off = 0;
  auto alloc = [&](size_t bytes) -> void* {
    void* p = ws + off;
    off += (bytes + 255) & ~(size_t)255;
    return p;
  };
  const size_t nx = (size_t)NBATCH * S_LEN * DHEAD;
  const size_t nqk = (size_t)NBATCH * NHEAD * S_LEN * DHEAD;
  const size_t nslots = (size_t)16 * NCHUNKF;  // 9216
  u16* xb = (u16*)alloc(nx * 2);
  u16* xT = (u16*)alloc(nx * 2);
  u16* Wqt = (u16*)alloc((size_t)NHEAD * DHEAD * DHEAD * 2);
  u16* Wkt = (u16*)alloc((size_t)NHEAD * DHEAD * DHEAD * 2);
  u16* WoB = (u16*)alloc((size_t)DHEAD * NHEAD * DHEAD * 2);
  u16* Qb = (u16*)alloc(nqk * 2);
  u16* Kb = (u16*)alloc(nqk * 2);
  u16* Yb = (u16*)alloc(nqk * 2);
  float* yPart = (float*)alloc(nslots * 32 * 128 * 4);  // 151 MB
  float* rsPart = (float*)alloc(nslots * 32 * 4);       // 1.2 MB
  (void)ws_size;

  k_conv_x<<<dim3(nx / 256), dim3(256), 0, stream>>>(x, xb, xT);
  k_conv_w<<<dim3(131072 / 256), dim3(256), 0, stream>>>(Wq, Wk, Wo, Wqt, Wkt, WoB);
  k_proj<<<dim3(S_LEN / 32 / 4, NHEAD, 2 * NBATCH), dim3(256), 0, stream>>>(xb, Wqt, Wkt, Qb, Kb);
  k_attn<<<dim3(16 * NCHUNKF), dim3(64), 0, stream>>>(Qb, Kb, xT, yPart, rsPart);
  k_comb<<<dim3(16 * (S_LEN / 32) / 4), dim3(256), 0, stream>>>(yPart, rsPart, Yb);
  k_oproj<<<dim3((NBATCH * S_LEN) / 32 / 4, 2, 2), dim3(256), 0, stream>>>(Yb, WoB, out);
}

// Round 8
// 358.993 us; speedup vs baseline: 1.0103x; 1.0103x over previous
//
#include <hip/hip_runtime.h>
#include <hip/hip_bf16.h>

typedef unsigned short u16;
typedef unsigned int u32;
typedef __attribute__((ext_vector_type(8))) short bf16x8;
typedef __attribute__((ext_vector_type(4))) float f32x4;

#define S_LEN 4096
#define DHEAD 128
#define NHEAD 8
#define NBATCH 2

__device__ __forceinline__ u16 f2b(float f) {
  __hip_bfloat16 h = __float2bfloat16(f);
  return *(u16*)&h;
}

__device__ __forceinline__ f32x4 mfma16(bf16x8 a, bf16x8 b, f32x4 c) {
  return __builtin_amdgcn_mfma_f32_16x16x32_bf16(a, b, c, 0, 0, 0);
}

__device__ __forceinline__ f32x4 zero4() { f32x4 z = {0.f, 0.f, 0.f, 0.f}; return z; }

// ---------------- converts ----------------
__global__ void k_conv_x(const float* __restrict__ x, u16* __restrict__ xb,
                         u16* __restrict__ xT) {
  int idx = blockIdx.x * blockDim.x + threadIdx.x;
  float v = x[idx];
  u16 bv = f2b(v);
  xb[idx] = bv;
  int d = idx & 127;
  int bs = idx >> 7;
  int b = bs >> 12;
  int s = bs & 4095;
  xT[((size_t)b * DHEAD + d) * S_LEN + s] = bv;
}

__global__ void k_conv_w(const float* __restrict__ Wq, const float* __restrict__ Wk,
                         const float* __restrict__ Wo, u16* __restrict__ Wqt,
                         u16* __restrict__ Wkt, u16* __restrict__ WoB) {
  int idx = blockIdx.x * blockDim.x + threadIdx.x;
  int h = idx >> 14;
  int d = (idx >> 7) & 127;
  int e = idx & 127;
  int t = (h << 14) + (e << 7) + d;
  Wqt[t] = f2b(Wq[idx]);
  Wkt[t] = f2b(Wk[idx]);
  WoB[idx] = f2b(Wo[idx]);
}

// ---------------- Q/K projection: 4 waves/block ----------------
__global__ __launch_bounds__(256) void k_proj(const u16* __restrict__ xb,
                                              const u16* __restrict__ Wqt,
                                              const u16* __restrict__ Wkt,
                                              u16* __restrict__ Qb, u16* __restrict__ Kb) {
  int wid = threadIdx.x >> 6;
  int lane = threadIdx.x & 63;
  int qt = blockIdx.x * 4 + wid;
  int h = blockIdx.y, z = blockIdx.z;
  int b = z >> 1, w = z & 1;
  int row16 = lane & 15, kgrp = lane >> 4;
  int sb = qt * 32;
  const u16* xp = xb + ((size_t)b * S_LEN + sb) * DHEAD;
  bf16x8 a[2][4];
#pragma unroll
  for (int r = 0; r < 2; ++r)
#pragma unroll
    for (int kc = 0; kc < 4; ++kc)
      a[r][kc] = *(const bf16x8*)(xp + (r * 16 + row16) * DHEAD + kc * 32 + kgrp * 8);

  const u16* Wt = (w == 0 ? Wqt : Wkt) + (size_t)h * DHEAD * DHEAD;
  u16* Out = (w == 0 ? Qb : Kb) + ((size_t)(b * NHEAD + h) * S_LEN + sb) * DHEAD;
  f32x4 acc[2][8];
#pragma unroll
  for (int r = 0; r < 2; ++r)
#pragma unroll
    for (int nc = 0; nc < 8; ++nc) acc[r][nc] = zero4();
#pragma unroll
  for (int kc = 0; kc < 4; ++kc)
#pragma unroll
    for (int nc = 0; nc < 8; ++nc) {
      bf16x8 bw = *(const bf16x8*)(Wt + (nc * 16 + row16) * DHEAD + kc * 32 + kgrp * 8);
      acc[0][nc] = mfma16(a[0][kc], bw, acc[0][nc]);
      acc[1][nc] = mfma16(a[1][kc], bw, acc[1][nc]);
    }
#pragma unroll
  for (int r = 0; r < 2; ++r)
#pragma unroll
    for (int nc = 0; nc < 8; ++nc)
#pragma unroll
      for (int i = 0; i < 4; ++i)
        Out[(size_t)(r * 16 + kgrp * 4 + i) * DHEAD + nc * 16 + row16] =
            f2b(acc[r][nc][i]);
}

// ---------------- causal flash attention ----------------
// 1 wave per block; 32 q-rows; full key range.
// __launch_bounds__(64,2): force combined VGPR+AGPR <= 256 so 2 waves/SIMD fit
// (the ~300-reg default allocation capped every prior round at 1 wave/SIMD).
__global__ __launch_bounds__(64, 2) void k_attn(const u16* __restrict__ Qb,
                                                const u16* __restrict__ Kb,
                                                const u16* __restrict__ xT,
                                                u16* __restrict__ Yb) {
  int p = blockIdx.x;
  int xcd = p & 7;
  int j = p >> 3;                        // 0..255
  int pair = xcd + (j >= 128 ? 8 : 0);   // 0..15 (same (b,h) per XCD)
  int qt = 127 - (j & 127);              // longest first (LPT)
  int b = pair >> 3;
  int h = pair & 7;

  int lane = threadIdx.x;
  int row16 = lane & 15, kgrp = lane >> 4;
  int qb0 = qt * 32;

  const u16* Qp = Qb + ((size_t)(b * NHEAD + h) * S_LEN + qb0) * DHEAD;
  const u16* Kp = Kb + (size_t)(b * NHEAD + h) * S_LEN * DHEAD;
  const u16* Vt = xT + (size_t)b * DHEAD * S_LEN;

  bf16x8 aq[2][4];
#pragma unroll
  for (int r = 0; r < 2; ++r)
#pragma unroll
    for (int kc = 0; kc < 4; ++kc)
      aq[r][kc] = *(const bf16x8*)(Qp + (r * 16 + row16) * DHEAD + kc * 32 + kgrp * 8);

  f32x4 y[2][8];
#pragma unroll
  for (int r = 0; r < 2; ++r)
#pragma unroll
    for (int nc = 0; nc < 8; ++nc) y[r][nc] = zero4();
  f32x4 rs[2];
  rs[0] = zero4();
  rs[1] = zero4();

  __shared__ __align__(16) u16 plds[2][32][40];

  bf16x8 kbufA[8], kbufB[8];

  auto loadK = [&](bf16x8 (&dst)[8], int k0) {
#pragma unroll
    for (int nk = 0; nk < 2; ++nk)
#pragma unroll
      for (int kc = 0; kc < 4; ++kc)
        dst[nk * 4 + kc] = *(const bf16x8*)(Kp + (size_t)(k0 + nk * 16 + row16) * DHEAD +
                                            kc * 32 + kgrp * 8);
  };

  const float c2 = 0.12754274816295166f;    // (1/sqrt(128)) * log2(e)
  const float clip2 = 14.426950408889634f;  // 10 * log2(e)

  auto body = [&](bf16x8 (&kc_)[8], bf16x8 (&kn_)[8], int kt) {
    int k0 = kt * 32;
    int cur = kt & 1;
    // first half of V (16 live regs instead of 32)
    bf16x8 vreg0[4];
#pragma unroll
    for (int nc = 0; nc < 4; ++nc)
      vreg0[nc] = *(const bf16x8*)(Vt + (size_t)(nc * 16 + row16) * S_LEN + k0 + kgrp * 8);
    int kn0 = (kt < qt) ? k0 + 32 : k0;
    loadK(kn_, kn0);

    f32x4 sc[2][2];
    sc[0][0] = zero4(); sc[0][1] = zero4(); sc[1][0] = zero4(); sc[1][1] = zero4();
#pragma unroll
    for (int nk = 0; nk < 2; ++nk)
#pragma unroll
      for (int kcc = 0; kcc < 4; ++kcc) {
        sc[0][nk] = mfma16(aq[0][kcc], kc_[nk * 4 + kcc], sc[0][nk]);
        sc[1][nk] = mfma16(aq[1][kcc], kc_[nk * 4 + kcc], sc[1][nk]);
      }

    // second half of V, issued ahead of its PV use
    bf16x8 vreg1[4];
#pragma unroll
    for (int nc = 0; nc < 4; ++nc)
      vreg1[nc] =
          *(const bf16x8*)(Vt + (size_t)((nc + 4) * 16 + row16) * S_LEN + k0 + kgrp * 8);

#pragma unroll
    for (int r = 0; r < 2; ++r)
#pragma unroll
      for (int nk = 0; nk < 2; ++nk) {
        int key = k0 + nk * 16 + row16;
#pragma unroll
        for (int i = 0; i < 4; ++i) {
          float v = sc[r][nk][i] * c2;
          v = fminf(fmaxf(v, -clip2), clip2);
          float pcur = __builtin_amdgcn_exp2f(v);
          int qrow = qb0 + r * 16 + kgrp * 4 + i;
          pcur = (key > qrow) ? 0.0f : pcur;   // branchless; fires only on diag tile
          rs[r][i] += pcur;
          plds[cur][r * 16 + kgrp * 4 + i][nk * 16 + row16] = f2b(pcur);
        }
      }
    bf16x8 ap0 = *(const bf16x8*)&plds[cur][row16][kgrp * 8];
    bf16x8 ap1 = *(const bf16x8*)&plds[cur][16 + row16][kgrp * 8];
#pragma unroll
    for (int nc = 0; nc < 4; ++nc) {
      y[0][nc] = mfma16(ap0, vreg0[nc], y[0][nc]);
      y[1][nc] = mfma16(ap1, vreg0[nc], y[1][nc]);
    }
#pragma unroll
    for (int nc = 0; nc < 4; ++nc) {
      y[0][nc + 4] = mfma16(ap0, vreg1[nc], y[0][nc + 4]);
      y[1][nc + 4] = mfma16(ap1, vreg1[nc], y[1][nc + 4]);
    }
  };

  loadK(kbufA, 0);
  int kt = 0;
  while (true) {
    body(kbufA, kbufB, kt);
    if (kt == qt) break;
    ++kt;
    body(kbufB, kbufA, kt);
    if (kt == qt) break;
    ++kt;
  }

  // reduce rs over the 16 row16 lanes of each kgrp group
#pragma unroll
  for (int r = 0; r < 2; ++r)
#pragma unroll
    for (int i = 0; i < 4; ++i) {
      float v = rs[r][i];
      v += __shfl_xor(v, 1, 64);
      v += __shfl_xor(v, 2, 64);
      v += __shfl_xor(v, 4, 64);
      v += __shfl_xor(v, 8, 64);
      rs[r][i] = v;
    }

  u16* Yp = Yb + ((size_t)b * S_LEN + qb0) * (NHEAD * DHEAD) + h * DHEAD;
#pragma unroll
  for (int r = 0; r < 2; ++r) {
    float inv[4];
#pragma unroll
    for (int i = 0; i < 4; ++i) inv[i] = 1.0f / rs[r][i];
#pragma unroll
    for (int nc = 0; nc < 8; ++nc)
#pragma unroll
      for (int i = 0; i < 4; ++i)
        Yp[(size_t)(r * 16 + kgrp * 4 + i) * (NHEAD * DHEAD) + nc * 16 + row16] =
            f2b(y[r][nc][i] * inv[i]);
  }
}

// ---------------- output projection: 4 waves/block ----------------
__global__ __launch_bounds__(256) void k_oproj(const u16* __restrict__ Yb,
                                               const u16* __restrict__ WoB,
                                               float* __restrict__ out) {
  int wid = threadIdx.x >> 6;
  int lane = threadIdx.x & 63;
  int mb = (blockIdx.x * 4 + wid) * 32 + blockIdx.y * 16;
  int nb = blockIdx.z * 64;
  int row16 = lane & 15, kgrp = lane >> 4;
  f32x4 acc[4];
#pragma unroll
  for (int nc = 0; nc < 4; ++nc) acc[nc] = zero4();
#pragma unroll 4
  for (int kc = 0; kc < 32; ++kc) {
    bf16x8 a0 = *(const bf16x8*)(Yb + (size_t)(mb + row16) * 1024 + kc * 32 + kgrp * 8);
#pragma unroll
    for (int nc = 0; nc < 4; ++nc) {
      bf16x8 bw =
          *(const bf16x8*)(WoB + (size_t)(nb + nc * 16 + row16) * 1024 + kc * 32 + kgrp * 8);
      acc[nc] = mfma16(a0, bw, acc[nc]);
    }
  }
#pragma unroll
  for (int nc = 0; nc < 4; ++nc)
#pragma unroll
    for (int i = 0; i < 4; ++i)
      out[(size_t)(mb + kgrp * 4 + i) * DHEAD + nb + nc * 16 + row16] = acc[nc][i];
}

extern "C" void kernel_launch(void* const* d_in, const int* in_sizes, int n_in,
                              void* d_out, int out_size, void* d_ws, size_t ws_size,
                              hipStream_t stream) {
  const float* x = (const float*)d_in[0];
  const float* Wq = (const float*)d_in[1];
  const float* Wk = (const float*)d_in[2];
  const float* Wo = (const float*)d_in[3];
  float* out = (float*)d_out;

  char* ws = (char*)d_ws;
  size_t off = 0;
  auto alloc = [&](size_t bytes) -> void* {
    void* p = ws + off;
    off += (bytes + 255) & ~(size_t)255;
    return p;
  };
  const size_t nx = (size_t)NBATCH * S_LEN * DHEAD;
  const size_t nqk = (size_t)NBATCH * NHEAD * S_LEN * DHEAD;
  u16* xb = (u16*)alloc(nx * 2);
  u16* xT = (u16*)alloc(nx * 2);
  u16* Wqt = (u16*)alloc((size_t)NHEAD * DHEAD * DHEAD * 2);
  u16* Wkt = (u16*)alloc((size_t)NHEAD * DHEAD * DHEAD * 2);
  u16* WoB = (u16*)alloc((size_t)DHEAD * NHEAD * DHEAD * 2);
  u16* Qb = (u16*)alloc(nqk * 2);
  u16* Kb = (u16*)alloc(nqk * 2);
  u16* Yb = (u16*)alloc(nqk * 2);
  (void)ws_size;

  k_conv_x<<<dim3(nx / 256), dim3(256), 0, stream>>>(x, xb, xT);
  k_conv_w<<<dim3(131072 / 256), dim3(256), 0, stream>>>(Wq, Wk, Wo, Wqt, Wkt, WoB);
  k_proj<<<dim3(S_LEN / 32 / 4, NHEAD, 2 * NBATCH), dim3(256), 0, stream>>>(xb, Wqt, Wkt, Qb, Kb);
  k_attn<<<dim3((S_LEN / 32) * NHEAD * NBATCH), dim3(64), 0, stream>>>(Qb, Kb, xT, Yb);
  k_oproj<<<dim3((NBATCH * S_LEN) / 32 / 4, 2, 2), dim3(256), 0, stream>>>(Yb, WoB, out);
}

// Round 9
// 209.463 us; speedup vs baseline: 1.7315x; 1.7139x over previous
//
#include <hip/hip_runtime.h>
#include <hip/hip_bf16.h>

typedef unsigned short u16;
typedef unsigned int u32;
typedef __attribute__((ext_vector_type(8))) short bf16x8;
typedef __attribute__((ext_vector_type(4))) float f32x4;

#define S_LEN 4096
#define DHEAD 128
#define NHEAD 8
#define NBATCH 2
#define KSTRIDE 136   // u16; 272B row -> slot=(row+4kc+kgrp)&7 even spread
#define VSTRIDE 72    // u16; 144B row -> slot=(d+4kk+kgrp)&7 even spread

__device__ __forceinline__ u16 f2b(float f) {
  __hip_bfloat16 h = __float2bfloat16(f);
  return *(u16*)&h;
}

__device__ __forceinline__ f32x4 mfma16(bf16x8 a, bf16x8 b, f32x4 c) {
  return __builtin_amdgcn_mfma_f32_16x16x32_bf16(a, b, c, 0, 0, 0);
}

__device__ __forceinline__ f32x4 zero4() { f32x4 z = {0.f, 0.f, 0.f, 0.f}; return z; }

// ---------------- converts ----------------
__global__ void k_conv_x(const float* __restrict__ x, u16* __restrict__ xb,
                         u16* __restrict__ xT) {
  int idx = blockIdx.x * blockDim.x + threadIdx.x;
  float v = x[idx];
  u16 bv = f2b(v);
  xb[idx] = bv;
  int d = idx & 127;
  int bs = idx >> 7;
  int b = bs >> 12;
  int s = bs & 4095;
  xT[((size_t)b * DHEAD + d) * S_LEN + s] = bv;
}

__global__ void k_conv_w(const float* __restrict__ Wq, const float* __restrict__ Wk,
                         const float* __restrict__ Wo, u16* __restrict__ Wqt,
                         u16* __restrict__ Wkt, u16* __restrict__ WoB) {
  int idx = blockIdx.x * blockDim.x + threadIdx.x;
  int h = idx >> 14;
  int d = (idx >> 7) & 127;
  int e = idx & 127;
  int t = (h << 14) + (e << 7) + d;
  Wqt[t] = f2b(Wq[idx]);
  Wkt[t] = f2b(Wk[idx]);
  WoB[idx] = f2b(Wo[idx]);
}

// ---------------- Q/K projection: 4 waves/block ----------------
__global__ __launch_bounds__(256) void k_proj(const u16* __restrict__ xb,
                                              const u16* __restrict__ Wqt,
                                              const u16* __restrict__ Wkt,
                                              u16* __restrict__ Qb, u16* __restrict__ Kb) {
  int wid = threadIdx.x >> 6;
  int lane = threadIdx.x & 63;
  int qt = blockIdx.x * 4 + wid;
  int h = blockIdx.y, z = blockIdx.z;
  int b = z >> 1, w = z & 1;
  int row16 = lane & 15, kgrp = lane >> 4;
  int sb = qt * 32;
  const u16* xp = xb + ((size_t)b * S_LEN + sb) * DHEAD;
  bf16x8 a[2][4];
#pragma unroll
  for (int r = 0; r < 2; ++r)
#pragma unroll
    for (int kc = 0; kc < 4; ++kc)
      a[r][kc] = *(const bf16x8*)(xp + (r * 16 + row16) * DHEAD + kc * 32 + kgrp * 8);

  const u16* Wt = (w == 0 ? Wqt : Wkt) + (size_t)h * DHEAD * DHEAD;
  u16* Out = (w == 0 ? Qb : Kb) + ((size_t)(b * NHEAD + h) * S_LEN + sb) * DHEAD;
  f32x4 acc[2][8];
#pragma unroll
  for (int r = 0; r < 2; ++r)
#pragma unroll
    for (int nc = 0; nc < 8; ++nc) acc[r][nc] = zero4();
#pragma unroll
  for (int kc = 0; kc < 4; ++kc)
#pragma unroll
    for (int nc = 0; nc < 8; ++nc) {
      bf16x8 bw = *(const bf16x8*)(Wt + (nc * 16 + row16) * DHEAD + kc * 32 + kgrp * 8);
      acc[0][nc] = mfma16(a[0][kc], bw, acc[0][nc]);
      acc[1][nc] = mfma16(a[1][kc], bw, acc[1][nc]);
    }
#pragma unroll
  for (int r = 0; r < 2; ++r)
#pragma unroll
    for (int nc = 0; nc < 8; ++nc)
#pragma unroll
      for (int i = 0; i < 4; ++i)
        Out[(size_t)(r * 16 + kgrp * 4 + i) * DHEAD + nc * 16 + row16] =
            f2b(acc[r][nc][i]);
}

// ---------------- causal flash attention: block-cooperative LDS staging -------
// 4 waves/block, QBLK=128 (wave w: rows qb0+32w..+31), KVBLK=64.
// K/V staged ONCE per block per tile with coalesced 1KB/instr loads; fragments
// come from LDS -> vector-memory address traffic cut ~16x vs per-wave L2 pulls.
__global__ __launch_bounds__(256) void k_attn(const u16* __restrict__ Qb,
                                              const u16* __restrict__ Kb,
                                              const u16* __restrict__ xT,
                                              u16* __restrict__ Yb) {
  int p = blockIdx.x;                      // 0..511
  int xcd = p & 7;
  int j = p >> 3;                          // 0..63
  int pair = xcd + (j >= 32 ? 8 : 0);      // 0..15 (same (b,h) per XCD)
  int qblk = 31 - (j & 31);                // longest first (LPT)
  int b = pair >> 3, h = pair & 7;
  int qb0 = qblk * 128;

  int tid = threadIdx.x;
  int wid = tid >> 6;
  int lane = tid & 63;
  int row16 = lane & 15, kgrp = lane >> 4;
  int qw = qb0 + wid * 32;                 // this wave's 32 q-rows

  const u16* Qp = Qb + ((size_t)(b * NHEAD + h) * S_LEN + qw) * DHEAD;
  const u16* Kp = Kb + (size_t)(b * NHEAD + h) * S_LEN * DHEAD;
  const u16* Vt = xT + (size_t)b * DHEAD * S_LEN;

  __shared__ __align__(16) u16 Klds[64 * KSTRIDE];    // 17.0 KB
  __shared__ __align__(16) u16 Vlds[128 * VSTRIDE];   // 18.0 KB
  __shared__ __align__(16) u16 plds[4][32][40];       // 10.0 KB (per-wave P)

  bf16x8 aq[2][4];
#pragma unroll
  for (int r = 0; r < 2; ++r)
#pragma unroll
    for (int kc = 0; kc < 4; ++kc)
      aq[r][kc] = *(const bf16x8*)(Qp + (r * 16 + row16) * DHEAD + kc * 32 + kgrp * 8);

  f32x4 y[2][8];
#pragma unroll
  for (int r = 0; r < 2; ++r)
#pragma unroll
    for (int nc = 0; nc < 8; ++nc) y[r][nc] = zero4();
  f32x4 rs[2];
  rs[0] = zero4();
  rs[1] = zero4();

  const float c2 = 0.12754274816295166f;    // (1/sqrt(128)) * log2(e)
  const float clip2 = 14.426950408889634f;  // 10 * log2(e)

  bf16x8 kst[4], vst[4];  // staging regs (static-indexed via full unroll)

  auto issueK = [&](int k0) {
#pragma unroll
    for (int r2 = 0; r2 < 4; ++r2) {
      int idx = r2 * 256 + tid;
      int row = idx >> 4, cg = idx & 15;
      kst[r2] = *(const bf16x8*)(Kp + (size_t)(k0 + row) * DHEAD + cg * 8);
    }
  };
  auto issueV = [&](int k0) {
#pragma unroll
    for (int r2 = 0; r2 < 4; ++r2) {
      int idx = r2 * 256 + tid;
      int d = idx >> 3, pg = idx & 7;
      vst[r2] = *(const bf16x8*)(Vt + (size_t)d * S_LEN + k0 + pg * 8);
    }
  };
  auto writeKV = [&]() {
#pragma unroll
    for (int r2 = 0; r2 < 4; ++r2) {
      int idx = r2 * 256 + tid;
      int row = idx >> 4, cg = idx & 15;
      *(bf16x8*)&Klds[row * KSTRIDE + cg * 8] = kst[r2];
    }
#pragma unroll
    for (int r2 = 0; r2 < 4; ++r2) {
      int idx = r2 * 256 + tid;
      int d = idx >> 3, pg = idx & 7;
      *(bf16x8*)&Vlds[d * VSTRIDE + pg * 8] = vst[r2];
    }
  };

  // compute one 32-key subtile (kk = 0/1) of the staged 64-key tile
  auto subtile = [&](int k0, int kk) {
    bf16x8 kf[8];
#pragma unroll
    for (int nk = 0; nk < 2; ++nk)
#pragma unroll
      for (int kc = 0; kc < 4; ++kc)
        kf[nk * 4 + kc] = *(const bf16x8*)&Klds[(kk * 32 + nk * 16 + row16) * KSTRIDE +
                                                kc * 32 + kgrp * 8];
    f32x4 sc[2][2];
    sc[0][0] = zero4(); sc[0][1] = zero4(); sc[1][0] = zero4(); sc[1][1] = zero4();
#pragma unroll
    for (int nk = 0; nk < 2; ++nk)
#pragma unroll
      for (int kcc = 0; kcc < 4; ++kcc) {
        sc[0][nk] = mfma16(aq[0][kcc], kf[nk * 4 + kcc], sc[0][nk]);
        sc[1][nk] = mfma16(aq[1][kcc], kf[nk * 4 + kcc], sc[1][nk]);
      }
#pragma unroll
    for (int r = 0; r < 2; ++r)
#pragma unroll
      for (int nk = 0; nk < 2; ++nk) {
        int key = k0 + kk * 32 + nk * 16 + row16;
#pragma unroll
        for (int i = 0; i < 4; ++i) {
          float v = sc[r][nk][i] * c2;
          v = fminf(fmaxf(v, -clip2), clip2);
          float pcur = __builtin_amdgcn_exp2f(v);
          int qrow = qw + r * 16 + kgrp * 4 + i;
          pcur = (key > qrow) ? 0.0f : pcur;   // branchless causal mask
          rs[r][i] += pcur;
          plds[wid][r * 16 + kgrp * 4 + i][nk * 16 + row16] = f2b(pcur);
        }
      }
    bf16x8 ap0 = *(const bf16x8*)&plds[wid][row16][kgrp * 8];
    bf16x8 ap1 = *(const bf16x8*)&plds[wid][16 + row16][kgrp * 8];
#pragma unroll
    for (int nc = 0; nc < 8; ++nc) {
      bf16x8 vf = *(const bf16x8*)&Vlds[(nc * 16 + row16) * VSTRIDE + kk * 32 + kgrp * 8];
      y[0][nc] = mfma16(ap0, vf, y[0][nc]);
      y[1][nc] = mfma16(ap1, vf, y[1][nc]);
    }
  };

  int NT = qb0 / 64 + 2;  // key tiles covering keys 0..qb0+127

  // prologue: stage tile 0
  issueK(0);
  issueV(0);
  writeKV();
  __syncthreads();

  for (int t = 0; t < NT; ++t) {
    int k0 = t * 64;
    bool more = (t + 1 < NT);
    if (more) {           // issue next tile's global loads early (T14)
      issueK(k0 + 64);
      issueV(k0 + 64);
    }
    subtile(k0, 0);       // compute hides the in-flight loads
    subtile(k0, 1);
    __syncthreads();      // all waves done reading Klds/Vlds
    if (more) {
      writeKV();          // vmcnt wait inserted by compiler before ds_write
      __syncthreads();    // staged tile visible to all waves
    }
  }

  // reduce rs over the 16 row16 lanes of each kgrp group
#pragma unroll
  for (int r = 0; r < 2; ++r)
#pragma unroll
    for (int i = 0; i < 4; ++i) {
      float v = rs[r][i];
      v += __shfl_xor(v, 1, 64);
      v += __shfl_xor(v, 2, 64);
      v += __shfl_xor(v, 4, 64);
      v += __shfl_xor(v, 8, 64);
      rs[r][i] = v;
    }

  u16* Yp = Yb + ((size_t)b * S_LEN + qw) * (NHEAD * DHEAD) + h * DHEAD;
#pragma unroll
  for (int r = 0; r < 2; ++r) {
    float inv[4];
#pragma unroll
    for (int i = 0; i < 4; ++i) inv[i] = 1.0f / rs[r][i];
#pragma unroll
    for (int nc = 0; nc < 8; ++nc)
#pragma unroll
      for (int i = 0; i < 4; ++i)
        Yp[(size_t)(r * 16 + kgrp * 4 + i) * (NHEAD * DHEAD) + nc * 16 + row16] =
            f2b(y[r][nc][i] * inv[i]);
  }
}

// ---------------- output projection: 4 waves/block ----------------
__global__ __launch_bounds__(256) void k_oproj(const u16* __restrict__ Yb,
                                               const u16* __restrict__ WoB,
                                               float* __restrict__ out) {
  int wid = threadIdx.x >> 6;
  int lane = threadIdx.x & 63;
  int mb = (blockIdx.x * 4 + wid) * 32 + blockIdx.y * 16;
  int nb = blockIdx.z * 64;
  int row16 = lane & 15, kgrp = lane >> 4;
  f32x4 acc[4];
#pragma unroll
  for (int nc = 0; nc < 4; ++nc) acc[nc] = zero4();
#pragma unroll 4
  for (int kc = 0; kc < 32; ++kc) {
    bf16x8 a0 = *(const bf16x8*)(Yb + (size_t)(mb + row16) * 1024 + kc * 32 + kgrp * 8);
#pragma unroll
    for (int nc = 0; nc < 4; ++nc) {
      bf16x8 bw =
          *(const bf16x8*)(WoB + (size_t)(nb + nc * 16 + row16) * 1024 + kc * 32 + kgrp * 8);
      acc[nc] = mfma16(a0, bw, acc[nc]);
    }
  }
#pragma unroll
  for (int nc = 0; nc < 4; ++nc)
#pragma unroll
    for (int i = 0; i < 4; ++i)
      out[(size_t)(mb + kgrp * 4 + i) * DHEAD + nb + nc * 16 + row16] = acc[nc][i];
}

extern "C" void kernel_launch(void* const* d_in, const int* in_sizes, int n_in,
                              void* d_out, int out_size, void* d_ws, size_t ws_size,
                              hipStream_t stream) {
  const float* x = (const float*)d_in[0];
  const float* Wq = (const float*)d_in[1];
  const float* Wk = (const float*)d_in[2];
  const float* Wo = (const float*)d_in[3];
  float* out = (float*)d_out;

  char* ws = (char*)d_ws;
  size_t off = 0;
  auto alloc = [&](size_t bytes) -> void* {
    void* p = ws + off;
    off += (bytes + 255) & ~(size_t)255;
    return p;
  };
  const size_t nx = (size_t)NBATCH * S_LEN * DHEAD;
  const size_t nqk = (size_t)NBATCH * NHEAD * S_LEN * DHEAD;
  u16* xb = (u16*)alloc(nx * 2);
  u16* xT = (u16*)alloc(nx * 2);
  u16* Wqt = (u16*)alloc((size_t)NHEAD * DHEAD * DHEAD * 2);
  u16* Wkt = (u16*)alloc((size_t)NHEAD * DHEAD * DHEAD * 2);
  u16* WoB = (u16*)alloc((size_t)DHEAD * NHEAD * DHEAD * 2);
  u16* Qb = (u16*)alloc(nqk * 2);
  u16* Kb = (u16*)alloc(nqk * 2);
  u16* Yb = (u16*)alloc(nqk * 2);
  (void)ws_size;

  k_conv_x<<<dim3(nx / 256), dim3(256), 0, stream>>>(x, xb, xT);
  k_conv_w<<<dim3(131072 / 256), dim3(256), 0, stream>>>(Wq, Wk, Wo, Wqt, Wkt, WoB);
  k_proj<<<dim3(S_LEN / 32 / 4, NHEAD, 2 * NBATCH), dim3(256), 0, stream>>>(xb, Wqt, Wkt, Qb, Kb);
  k_attn<<<dim3(16 * 32), dim3(256), 0, stream>>>(Qb, Kb, xT, Yb);
  k_oproj<<<dim3((NBATCH * S_LEN) / 32 / 4, 2, 2), dim3(256), 0, stream>>>(Yb, WoB, out);
}